// Round 1
// baseline (32.505 us; speedup 1.0000x reference)
//
#include <hip/hip_runtime.h>

#define NN 64
#define SS 50
#define CC 100

__global__ __launch_bounds__(256) void lmc_main(
    const float* __restrict__ logits,        // (N,S,C)
    const int*   __restrict__ target,        // (N,S)
    const int*   __restrict__ rel_candidate, // (N,S,C)
    const int*   __restrict__ target_num,    // (N,)
    const int*   __restrict__ rel_candidate_num, // (N,S)
    const float* __restrict__ mask,          // (N,S)
    const float* __restrict__ rel_weight,    // (N,S)
    double*      __restrict__ ws)            // [0]=num, [1]=den
{
    const int tid  = threadIdx.x;
    const int lane = tid & 63;
    const int wid  = tid >> 6;                 // 0..3
    const int row  = blockIdx.x * 4 + wid;     // flat (b,s)

    double num = 0.0, den = 0.0;

    if (row < NN * SS) {
        const int b = row / SS;
        const int s = row - b * SS;

        if (lane == 0) den = (double)mask[row];

        if (s < target_num[b]) {
            int cn = rel_candidate_num[row];
            if (cn > CC) cn = CC;
            const int tgt = target[row];
            const int*   cand = rel_candidate + (size_t)row * CC;
            const float* lg   = logits        + (size_t)row * CC;

            const int c0 = lane;            // strip 0: c in [0,64)
            const int c1 = lane + 64;       // strip 1: c in [64,100)
            const bool m0 = (c0 < cn) && (cand[c0] == tgt);
            const bool m1 = (c1 < cn) && (c1 < CC) && (cand[c1] == tgt);

            // last-write-wins in the scatter => highest matching c
            const unsigned long long b1 = __ballot(m1);
            const unsigned long long b0 = __ballot(m0);

            int winlane = -1, strip = -1;
            if (b1)      { winlane = 63 - __clzll(b1); strip = 1; }
            else if (b0) { winlane = 63 - __clzll(b0); strip = 0; }

            if (winlane == lane) {
                const bool mine = (strip == 1) ? m1 : m0;
                if (mine) {
                    const int c = (strip == 1) ? c1 : c0;
                    num = -(double)lg[c] * (double)rel_weight[row];
                }
            }
        }
    }

    __shared__ double s_num[256];
    __shared__ double s_den[256];
    s_num[tid] = num;
    s_den[tid] = den;
    __syncthreads();
    #pragma unroll
    for (int off = 128; off > 0; off >>= 1) {
        if (tid < off) {
            s_num[tid] += s_num[tid + off];
            s_den[tid] += s_den[tid + off];
        }
        __syncthreads();
    }
    if (tid == 0) {
        atomicAdd(&ws[0], s_num[0]);
        atomicAdd(&ws[1], s_den[0]);
    }
}

__global__ void lmc_final(const double* __restrict__ ws, float* __restrict__ out) {
    out[0] = (float)(ws[0] / ws[1]);
}

extern "C" void kernel_launch(void* const* d_in, const int* in_sizes, int n_in,
                              void* d_out, int out_size, void* d_ws, size_t ws_size,
                              hipStream_t stream) {
    const float* logits            = (const float*)d_in[0];
    const int*   target            = (const int*)d_in[1];
    const int*   rel_candidate     = (const int*)d_in[2];
    // d_in[3] = rel_wordlist_num (scalar V) — not needed on device
    const int*   target_num        = (const int*)d_in[4];
    const int*   rel_candidate_num = (const int*)d_in[5];
    const float* mask              = (const float*)d_in[6];
    const float* rel_weight        = (const float*)d_in[7];
    float* out = (float*)d_out;
    double* ws = (double*)d_ws;

    // zero the two accumulators (graph-capture-safe async memset)
    hipMemsetAsync(ws, 0, 2 * sizeof(double), stream);

    const int rows = NN * SS;                 // 3200
    const int blocks = (rows + 3) / 4;        // 4 waves (rows) per 256-thread block
    lmc_main<<<blocks, 256, 0, stream>>>(logits, target, rel_candidate,
                                         target_num, rel_candidate_num,
                                         mask, rel_weight, ws);
    lmc_final<<<1, 1, 0, stream>>>(ws, out);
}

// Round 2
// 12.001 us; speedup vs baseline: 2.7086x; 2.7086x over previous
//
#include <hip/hip_runtime.h>

#define NN 64
#define SS 50
#define CC 100
#define ROWS (NN * SS)            // 3200
#define RPW 8                     // rows per wave
#define WPB 4                     // waves per block (256 threads)
#define NBLK (ROWS / (RPW * WPB)) // 100 blocks

__global__ __launch_bounds__(256) void lmc_main(
    const float* __restrict__ logits,            // (N,S,C)
    const int*   __restrict__ target,            // (N,S)
    const int*   __restrict__ rel_candidate,     // (N,S,C)
    const int*   __restrict__ target_num,        // (N,)
    const int*   __restrict__ rel_candidate_num, // (N,S)
    const float* __restrict__ mask,              // (N,S)
    const float* __restrict__ rel_weight,        // (N,S)
    double*      __restrict__ partial)           // [2*NBLK]: num, den per block
{
    const int tid  = threadIdx.x;
    const int lane = tid & 63;
    const int wid  = tid >> 6;                     // 0..3
    const int row0 = blockIdx.x * (RPW * WPB) + wid * RPW;

    double num = 0.0;
    // den: 8 mask loads spread across lanes 0..7 (coalesced), summed by tree
    double den = (lane < RPW) ? (double)mask[row0 + lane] : 0.0;

    #pragma unroll
    for (int r = 0; r < RPW; ++r) {
        const int row = row0 + r;                  // wave-uniform
        const int b   = row / SS;
        const int s   = row - b * SS;

        if (s < target_num[b]) {                   // wave-uniform branch
            int cn = rel_candidate_num[row];
            if (cn > CC) cn = CC;
            const int tgt = target[row];
            const int* cand = rel_candidate + (size_t)row * CC;

            const int c0 = lane;                   // c in [0,64)
            const int c1 = lane + 64;              // c in [64,100)
            const bool m0 = (c0 < cn) && (cand[c0] == tgt);
            const bool m1 = (c1 < CC) && (c1 < cn) && (cand[c1] == tgt);

            // last-write-wins scatter => highest matching c wins
            const unsigned long long bb1 = __ballot(m1);
            const unsigned long long bb0 = __ballot(m0);

            if (bb1) {
                const int win = 63 - __clzll(bb1);
                if (lane == win)
                    num += -(double)logits[(size_t)row * CC + c1] *
                            (double)rel_weight[row];
            } else if (bb0) {
                const int win = 63 - __clzll(bb0);
                if (lane == win)
                    num += -(double)logits[(size_t)row * CC + c0] *
                            (double)rel_weight[row];
            }
        }
    }

    __shared__ double s_num[256];
    __shared__ double s_den[256];
    s_num[tid] = num;
    s_den[tid] = den;
    __syncthreads();
    #pragma unroll
    for (int off = 128; off > 0; off >>= 1) {
        if (tid < off) {
            s_num[tid] += s_num[tid + off];
            s_den[tid] += s_den[tid + off];
        }
        __syncthreads();
    }
    if (tid == 0) {
        partial[2 * blockIdx.x]     = s_num[0];
        partial[2 * blockIdx.x + 1] = s_den[0];
    }
}

__global__ __launch_bounds__(128) void lmc_final(
    const double* __restrict__ partial, float* __restrict__ out)
{
    const int tid = threadIdx.x;
    double n = (tid < NBLK) ? partial[2 * tid]     : 0.0;
    double d = (tid < NBLK) ? partial[2 * tid + 1] : 0.0;
    __shared__ double sn[128];
    __shared__ double sd[128];
    sn[tid] = n;
    sd[tid] = d;
    __syncthreads();
    #pragma unroll
    for (int off = 64; off > 0; off >>= 1) {
        if (tid < off) {
            sn[tid] += sn[tid + off];
            sd[tid] += sd[tid + off];
        }
        __syncthreads();
    }
    if (tid == 0) out[0] = (float)(sn[0] / sd[0]);
}

extern "C" void kernel_launch(void* const* d_in, const int* in_sizes, int n_in,
                              void* d_out, int out_size, void* d_ws, size_t ws_size,
                              hipStream_t stream) {
    const float* logits            = (const float*)d_in[0];
    const int*   target            = (const int*)d_in[1];
    const int*   rel_candidate     = (const int*)d_in[2];
    // d_in[3] = rel_wordlist_num (scalar) — unused on device
    const int*   target_num        = (const int*)d_in[4];
    const int*   rel_candidate_num = (const int*)d_in[5];
    const float* mask              = (const float*)d_in[6];
    const float* rel_weight        = (const float*)d_in[7];
    float*  out     = (float*)d_out;
    double* partial = (double*)d_ws;   // 2*NBLK doubles = 1.6 KB, all slots
                                       // written every call -> no init needed

    lmc_main<<<NBLK, 256, 0, stream>>>(logits, target, rel_candidate,
                                       target_num, rel_candidate_num,
                                       mask, rel_weight, partial);
    lmc_final<<<1, 128, 0, stream>>>(partial, out);
}